// Round 1
// baseline (251.196 us; speedup 1.0000x reference)
//
#include <hip/hip_runtime.h>
#include <math.h>

#define NS 4096
#define DD 768
#define NH 30          // N_HIPER
#define NCH 31         // NH+1 channels
#define NCHUNK 256
#define CS (NS / NCHUNK)   // 16 samples per chunk

// ---------------------------------------------------------------------------
// prep: per-sample cell base offsets, fractional coords, segment length
// ---------------------------------------------------------------------------
__global__ void prep_kernel(const float* __restrict__ samples,
                            const float* __restrict__ last_point,
                            int* __restrict__ c00, int* __restrict__ c10,
                            int* __restrict__ c01, int* __restrict__ c11,
                            float* __restrict__ dxv, float* __restrict__ dyv,
                            float* __restrict__ distv) {
    int s = blockIdx.x * blockDim.x + threadIdx.x;
    if (s >= NS) return;
    float x = samples[2*s+0];
    float y = samples[2*s+1];
    float xs = x + 4.0f, ys = y + 4.0f;
    int fx = (int)floorf(xs), cx = (int)ceilf(xs);
    int fy = (int)floorf(ys), cy = (int)ceilf(ys);
    dxv[s] = x - floorf(x);
    dyv[s] = y - floorf(y);
    float nx, ny;
    if (s == NS-1) { nx = last_point[0]; ny = last_point[1]; }
    else           { nx = samples[2*s+2]; ny = samples[2*s+3]; }
    float ex = nx - x, ey = ny - y;
    distv[s] = sqrtf(ex*ex + ey*ey);
    // element offset of cell (gx,gy) at n=0,d=0: ((gx*9+gy)*31)*768
    c00[s] = ((fx*9 + fy)*NCH)*DD;   // below-left   (fx,fy)
    c10[s] = ((cx*9 + fy)*NCH)*DD;   // below-right  (cx,fy)
    c01[s] = ((fx*9 + cy)*NCH)*DD;   // above-left   (fx,cy)
    c11[s] = ((cx*9 + cy)*NCH)*DD;   // above-right  (cx,cy)
}

// ---------------------------------------------------------------------------
// pass1: per-chunk sum of dd[s,d] (density slice n=NH only)
// ---------------------------------------------------------------------------
__global__ __launch_bounds__(DD) void pass1_kernel(
    const float* __restrict__ emb,
    const int* __restrict__ c00, const int* __restrict__ c10,
    const int* __restrict__ c01, const int* __restrict__ c11,
    const float* __restrict__ dxv, const float* __restrict__ dyv,
    const float* __restrict__ distv,
    float* __restrict__ chunk_sum) {
    const int d = threadIdx.x;     // 0..767
    const int c = blockIdx.x;      // chunk
    float sum = 0.f;
    const int s0 = c*CS;
    for (int i = 0; i < CS; ++i) {
        const int s = s0 + i;
        const float dx = dxv[s], dy = dyv[s], dist = distv[s];
        const float omdx = 1.f - dx, omdy = 1.f - dy;
        float e00 = emb[c00[s] + NH*DD + d];
        float e10 = emb[c10[s] + NH*DD + d];
        float e01 = emb[c01[s] + NH*DD + d];
        float e11 = emb[c11[s] + NH*DD + d];
        float below = e00*omdx + e10*dx;
        float above = e01*omdx + e11*dx;
        float e     = below*omdy + above*dy;
        sum += fmaxf(e, 0.f) * dist;
    }
    chunk_sum[c*DD + d] = sum;
}

// ---------------------------------------------------------------------------
// scan: exclusive prefix over chunks, per d
// ---------------------------------------------------------------------------
__global__ __launch_bounds__(DD) void scan_kernel(
    const float* __restrict__ chunk_sum, float* __restrict__ offs) {
    const int d = threadIdx.x;   // 0..767
    float run = 0.f;
    for (int c = 0; c < NCHUNK; ++c) {
        offs[c*DD + d] = run;
        run += chunk_sum[c*DD + d];
    }
}

// ---------------------------------------------------------------------------
// main: per-chunk accumulation of out[n,d] += w[s,d]*emb[s,n,d]
// 384 threads, each owns 2 consecutive d (float2 loads)
// ---------------------------------------------------------------------------
__global__ __launch_bounds__(384) void main_kernel(
    const float* __restrict__ emb,
    const int* __restrict__ c00, const int* __restrict__ c10,
    const int* __restrict__ c01, const int* __restrict__ c11,
    const float* __restrict__ dxv, const float* __restrict__ dyv,
    const float* __restrict__ distv,
    const float* __restrict__ offs,
    float* __restrict__ out) {
    const int t = threadIdx.x;       // 0..383
    const int c = blockIdx.x;        // chunk
    const int d0 = 2*t;
    float accx[NH], accy[NH];
    #pragma unroll
    for (int n = 0; n < NH; ++n) { accx[n] = 0.f; accy[n] = 0.f; }
    float cumx = offs[c*DD + d0];
    float cumy = offs[c*DD + d0 + 1];
    const int s0 = c*CS;
    for (int i = 0; i < CS; ++i) {
        const int s = s0 + i;
        const float dx = dxv[s], dy = dyv[s], dist = distv[s];
        const float omdx = 1.f - dx, omdy = 1.f - dy;
        const float* p00 = emb + c00[s] + d0;
        const float* p10 = emb + c10[s] + d0;
        const float* p01 = emb + c01[s] + d0;
        const float* p11 = emb + c11[s] + d0;
        // density channel (n = NH)
        float2 e00 = *(const float2*)(p00 + NH*DD);
        float2 e10 = *(const float2*)(p10 + NH*DD);
        float2 e01 = *(const float2*)(p01 + NH*DD);
        float2 e11 = *(const float2*)(p11 + NH*DD);
        float bx = e00.x*omdx + e10.x*dx;
        float by = e00.y*omdx + e10.y*dx;
        float ax = e01.x*omdx + e11.x*dx;
        float ay = e01.y*omdx + e11.y*dx;
        float evx = bx*omdy + ax*dy;
        float evy = by*omdy + ay*dy;
        float ddx_ = fmaxf(evx, 0.f) * dist;
        float ddy_ = fmaxf(evy, 0.f) * dist;
        float wx = expf(-cumx) * (1.f - expf(-ddx_));
        float wy = expf(-cumy) * (1.f - expf(-ddy_));
        cumx += ddx_;
        cumy += ddy_;
        #pragma unroll
        for (int n = 0; n < NH; ++n) {
            float2 f00 = *(const float2*)(p00 + n*DD);
            float2 f10 = *(const float2*)(p10 + n*DD);
            float2 f01 = *(const float2*)(p01 + n*DD);
            float2 f11 = *(const float2*)(p11 + n*DD);
            float blx = f00.x*omdx + f10.x*dx;
            float bly = f00.y*omdx + f10.y*dx;
            float alx = f01.x*omdx + f11.x*dx;
            float aly = f01.y*omdx + f11.y*dx;
            float enx = blx*omdy + alx*dy;
            float eny = bly*omdy + aly*dy;
            accx[n] += wx*enx;
            accy[n] += wy*eny;
        }
    }
    #pragma unroll
    for (int n = 0; n < NH; ++n) {
        atomicAdd(&out[n*DD + d0],     accx[n]);
        atomicAdd(&out[n*DD + d0 + 1], accy[n]);
    }
}

// ---------------------------------------------------------------------------
extern "C" void kernel_launch(void* const* d_in, const int* in_sizes, int n_in,
                              void* d_out, int out_size, void* d_ws, size_t ws_size,
                              hipStream_t stream) {
    const float* samples    = (const float*)d_in[0];
    const float* last_point = (const float*)d_in[1];
    const float* emb        = (const float*)d_in[2];
    float* out = (float*)d_out;

    char* ws = (char*)d_ws;
    int*   c00 = (int*)ws;        ws += NS*sizeof(int);
    int*   c10 = (int*)ws;        ws += NS*sizeof(int);
    int*   c01 = (int*)ws;        ws += NS*sizeof(int);
    int*   c11 = (int*)ws;        ws += NS*sizeof(int);
    float* dxv = (float*)ws;      ws += NS*sizeof(float);
    float* dyv = (float*)ws;      ws += NS*sizeof(float);
    float* distv = (float*)ws;    ws += NS*sizeof(float);
    float* chunk_sum = (float*)ws; ws += NCHUNK*DD*sizeof(float);
    float* offs = (float*)ws;     ws += NCHUNK*DD*sizeof(float);

    hipMemsetAsync(d_out, 0, (size_t)out_size*sizeof(float), stream);
    prep_kernel<<<(NS+255)/256, 256, 0, stream>>>(samples, last_point,
                                                  c00,c10,c01,c11, dxv,dyv,distv);
    pass1_kernel<<<NCHUNK, DD, 0, stream>>>(emb, c00,c10,c01,c11,
                                            dxv,dyv,distv, chunk_sum);
    scan_kernel<<<1, DD, 0, stream>>>(chunk_sum, offs);
    main_kernel<<<NCHUNK, 384, 0, stream>>>(emb, c00,c10,c01,c11,
                                            dxv,dyv,distv, offs, out);
}

// Round 2
// 48.291 us; speedup vs baseline: 5.2017x; 5.2017x over previous
//
#include <hip/hip_runtime.h>
#include <math.h>

#define NS 4096
#define DD 768
#define NH 30          // N_HIPER
#define NCH 31         // channels per cell
#define NCELL 81       // 9x9 grid
#define NCHUNK 512
#define CS (NS / NCHUNK)    // 8 samples per chunk
#define NPART 8             // sample partitions per cell in wacc
#define SPP (NS / NPART)    // 512 samples per partition

// ---------------------------------------------------------------------------
// prep: per-sample cell ids, bilinear coefs, segment length
// ---------------------------------------------------------------------------
__global__ void prep_kernel(const float* __restrict__ samples,
                            const float* __restrict__ last_point,
                            int4* __restrict__ cells,
                            float4* __restrict__ coefs,
                            float* __restrict__ distv) {
    int s = blockIdx.x * blockDim.x + threadIdx.x;
    if (s >= NS) return;
    float x = samples[2*s+0];
    float y = samples[2*s+1];
    float xs = x + 4.0f, ys = y + 4.0f;
    int fx = (int)floorf(xs), cx = (int)ceilf(xs);
    int fy = (int)floorf(ys), cy = (int)ceilf(ys);
    float dx = x - floorf(x);
    float dy = y - floorf(y);
    float nx, ny;
    if (s == NS-1) { nx = last_point[0]; ny = last_point[1]; }
    else           { nx = samples[2*s+2]; ny = samples[2*s+3]; }
    float ex = nx - x, ey = ny - y;
    distv[s] = sqrtf(ex*ex + ey*ey);
    // corner order: (fx,fy)·(1-dx)(1-dy), (cx,fy)·dx(1-dy), (fx,cy)·(1-dx)dy, (cx,cy)·dx·dy
    cells[s] = make_int4(fx*9+fy, cx*9+fy, fx*9+cy, cx*9+cy);
    coefs[s] = make_float4((1.f-dx)*(1.f-dy), dx*(1.f-dy), (1.f-dx)*dy, dx*dy);
}

// bilinear gather of 2 consecutive d from the density (or any) slice
__device__ __forceinline__ float2 bilin2(const float* __restrict__ emb,
                                         int4 cl, float4 cf, int off) {
    const float2 e0 = *(const float2*)(emb + (long)cl.x*NCH*DD + off);
    const float2 e1 = *(const float2*)(emb + (long)cl.y*NCH*DD + off);
    const float2 e2 = *(const float2*)(emb + (long)cl.z*NCH*DD + off);
    const float2 e3 = *(const float2*)(emb + (long)cl.w*NCH*DD + off);
    return make_float2(e0.x*cf.x + e1.x*cf.y + e2.x*cf.z + e3.x*cf.w,
                       e0.y*cf.x + e1.y*cf.y + e2.y*cf.z + e3.y*cf.w);
}

// ---------------------------------------------------------------------------
// pass1: per-chunk sum of dd[s,d]  (density channel only)
// ---------------------------------------------------------------------------
__global__ __launch_bounds__(384) void pass1_kernel(
    const float* __restrict__ emb, const int4* __restrict__ cells,
    const float4* __restrict__ coefs, const float* __restrict__ distv,
    float* __restrict__ chunk_sum) {
    const int c = blockIdx.x;
    const int d0 = 2*threadIdx.x;
    float sx = 0.f, sy = 0.f;
    #pragma unroll
    for (int i = 0; i < CS; ++i) {
        const int s = c*CS + i;
        int4 cl = cells[s]; float4 cf = coefs[s]; float dist = distv[s];
        float2 e = bilin2(emb, cl, cf, NH*DD + d0);
        sx += fmaxf(e.x, 0.f) * dist;
        sy += fmaxf(e.y, 0.f) * dist;
    }
    *(float2*)(chunk_sum + c*DD + d0) = make_float2(sx, sy);
}

// ---------------------------------------------------------------------------
// scan: exclusive prefix over 512 chunks, one block per d, wave scan
// ---------------------------------------------------------------------------
__global__ __launch_bounds__(64) void scan_kernel(
    const float* __restrict__ chunk_sum, float* __restrict__ offs) {
    const int d = blockIdx.x;          // 0..767
    const int lane = threadIdx.x;      // 0..63
    float v[8];
    #pragma unroll
    for (int k = 0; k < 8; ++k)
        v[k] = chunk_sum[(lane*8 + k)*DD + d];
    float tot = 0.f;
    #pragma unroll
    for (int k = 0; k < 8; ++k) tot += v[k];
    // inclusive wave scan of tot
    float x = tot;
    #pragma unroll
    for (int off = 1; off < 64; off <<= 1) {
        float y = __shfl_up(x, off);
        if (lane >= off) x += y;
    }
    float run = x - tot;   // exclusive
    #pragma unroll
    for (int k = 0; k < 8; ++k) {
        offs[(lane*8 + k)*DD + d] = run;
        run += v[k];
    }
}

// ---------------------------------------------------------------------------
// wk: materialize w[s,d] = exp(-cum_excl)*(1-exp(-dd))
// ---------------------------------------------------------------------------
__global__ __launch_bounds__(384) void w_kernel(
    const float* __restrict__ emb, const int4* __restrict__ cells,
    const float4* __restrict__ coefs, const float* __restrict__ distv,
    const float* __restrict__ offs, float* __restrict__ w) {
    const int c = blockIdx.x;
    const int d0 = 2*threadIdx.x;
    float2 cum = *(const float2*)(offs + c*DD + d0);
    #pragma unroll
    for (int i = 0; i < CS; ++i) {
        const int s = c*CS + i;
        int4 cl = cells[s]; float4 cf = coefs[s]; float dist = distv[s];
        float2 e = bilin2(emb, cl, cf, NH*DD + d0);
        float ddx = fmaxf(e.x, 0.f) * dist;
        float ddy = fmaxf(e.y, 0.f) * dist;
        float wx = __expf(-cum.x) * (1.f - __expf(-ddx));
        float wy = __expf(-cum.y) * (1.f - __expf(-ddy));
        *(float2*)(w + (long)s*DD + d0) = make_float2(wx, wy);
        cum.x += ddx;
        cum.y += ddy;
    }
}

// ---------------------------------------------------------------------------
// wacc: W[g,d] = sum over samples with corner g of coef*w[s,d]
// block = (cell g, sample-partition); LDS-compacted match list
// ---------------------------------------------------------------------------
__global__ __launch_bounds__(256) void wacc_kernel(
    const int4* __restrict__ cells, const float4* __restrict__ coefs,
    const float* __restrict__ w, float* __restrict__ W) {
    __shared__ int   s_idx[SPP];
    __shared__ float s_cf[SPP];
    __shared__ int   s_cnt;
    const int g    = blockIdx.x / NPART;
    const int part = blockIdx.x % NPART;
    const int t    = threadIdx.x;
    if (t == 0) s_cnt = 0;
    __syncthreads();
    const int base = part * SPP;
    #pragma unroll
    for (int i = 0; i < SPP; i += 256) {
        const int s = base + i + t;
        int4 cl = cells[s]; float4 cf = coefs[s];
        float c = 0.f;
        if (cl.x == g) c += cf.x;
        if (cl.y == g) c += cf.y;
        if (cl.z == g) c += cf.z;
        if (cl.w == g) c += cf.w;
        if (c != 0.f) {
            int idx = atomicAdd(&s_cnt, 1);
            s_idx[idx] = s;
            s_cf[idx]  = c;
        }
    }
    __syncthreads();
    const int cnt = s_cnt;
    float a0 = 0.f, a1 = 0.f, a2 = 0.f;
    for (int j = 0; j < cnt; ++j) {
        const int   s = s_idx[j];
        const float c = s_cf[j];
        const float* wr = w + (long)s*DD;
        a0 += c * wr[t];
        a1 += c * wr[t + 256];
        a2 += c * wr[t + 512];
    }
    atomicAdd(&W[g*DD + t      ], a0);
    atomicAdd(&W[g*DD + t + 256], a1);
    atomicAdd(&W[g*DD + t + 512], a2);
}

// ---------------------------------------------------------------------------
// final: out[n,d] = sum_g W[g,d] * T[g,n,d]   (table read exactly once)
// ---------------------------------------------------------------------------
__global__ __launch_bounds__(256) void final_kernel(
    const float* __restrict__ emb, const float* __restrict__ W,
    float* __restrict__ out) {
    const int n    = blockIdx.x / 3;
    const int part = blockIdx.x % 3;
    const int d    = part*256 + threadIdx.x;
    float a0 = 0.f, a1 = 0.f, a2 = 0.f, a3 = 0.f;
    int g = 0;
    #pragma unroll 4
    for (; g + 4 <= 80; g += 4) {
        a0 += W[(g+0)*DD + d] * emb[((g+0)*NCH + n)*DD + d];
        a1 += W[(g+1)*DD + d] * emb[((g+1)*NCH + n)*DD + d];
        a2 += W[(g+2)*DD + d] * emb[((g+2)*NCH + n)*DD + d];
        a3 += W[(g+3)*DD + d] * emb[((g+3)*NCH + n)*DD + d];
    }
    a0 += W[80*DD + d] * emb[(80*NCH + n)*DD + d];
    out[n*DD + d] = (a0 + a1) + (a2 + a3);
}

// ---------------------------------------------------------------------------
extern "C" void kernel_launch(void* const* d_in, const int* in_sizes, int n_in,
                              void* d_out, int out_size, void* d_ws, size_t ws_size,
                              hipStream_t stream) {
    const float* samples    = (const float*)d_in[0];
    const float* last_point = (const float*)d_in[1];
    const float* emb        = (const float*)d_in[2];
    float* out = (float*)d_out;

    char* ws = (char*)d_ws;
    int4*   cells = (int4*)ws;     ws += (size_t)NS*sizeof(int4);
    float4* coefs = (float4*)ws;   ws += (size_t)NS*sizeof(float4);
    float*  distv = (float*)ws;    ws += (size_t)NS*sizeof(float);
    float*  chunk_sum = (float*)ws; ws += (size_t)NCHUNK*DD*sizeof(float);
    float*  offs  = (float*)ws;    ws += (size_t)NCHUNK*DD*sizeof(float);
    float*  Wbuf  = (float*)ws;    ws += (size_t)NCELL*DD*sizeof(float);
    float*  wmat  = (float*)ws;    ws += (size_t)NS*DD*sizeof(float);

    hipMemsetAsync(Wbuf, 0, (size_t)NCELL*DD*sizeof(float), stream);
    prep_kernel<<<(NS+255)/256, 256, 0, stream>>>(samples, last_point,
                                                  cells, coefs, distv);
    pass1_kernel<<<NCHUNK, 384, 0, stream>>>(emb, cells, coefs, distv, chunk_sum);
    scan_kernel<<<DD, 64, 0, stream>>>(chunk_sum, offs);
    w_kernel<<<NCHUNK, 384, 0, stream>>>(emb, cells, coefs, distv, offs, wmat);
    wacc_kernel<<<NCELL*NPART, 256, 0, stream>>>(cells, coefs, wmat, Wbuf);
    final_kernel<<<NH*3, 256, 0, stream>>>(emb, Wbuf, out);
}